// Round 1
// 684.063 us; speedup vs baseline: 28.0800x; 28.0800x over previous
//
#include <hip/hip_runtime.h>
#include <stdint.h>

// Problem constants: B=4, S=2048, E=2048, H=16, HD=128
// Dtypes: inputs f32; OUTPUT f32. Intermediates bf16 (2% threshold).
#define BB 4
#define SS 2048
#define EE 2048
#define HH 16
#define HD 128
#define SCALE 0.08838834764831845f

typedef __attribute__((ext_vector_type(8))) short bf16x8;
typedef __attribute__((ext_vector_type(4))) float f32x4;

__device__ __forceinline__ unsigned short f2bf(float f) {
  union { float f; unsigned u; } v;
  v.f = f;
  unsigned r = (v.u + 0x7fffu + ((v.u >> 16) & 1u)) >> 16;
  return (unsigned short)r;
}
__device__ __forceinline__ float bf2f(unsigned short u) {
  union { unsigned u; float f; } v;
  v.u = ((unsigned)u) << 16;
  return v.f;
}

// async global->LDS, 16B per lane. LDS dest = wave-uniform base + lane*16.
__device__ __forceinline__ void lds16(const void* g, void* l) {
  __builtin_amdgcn_global_load_lds(
      (__attribute__((address_space(1))) void*)(uintptr_t)g,
      (__attribute__((address_space(3))) void*)(uintptr_t)l,
      16, 0, 0);
}

// ---------------- fp32 -> bf16 conversion ----------------
__global__ void cvt_f32_bf16(const float* __restrict__ src,
                             unsigned short* __restrict__ dst, int n4) {
  int i = blockIdx.x * blockDim.x + threadIdx.x;
  if (i >= n4) return;
  float4 v = ((const float4*)src)[i];
  ushort4 o;
  o.x = f2bf(v.x); o.y = f2bf(v.y); o.z = f2bf(v.z); o.w = f2bf(v.w);
  ((ushort4*)dst)[i] = o;
}

// ---------------- m97-style bt-GEMM core ----------------
__device__ __forceinline__ void gemm_bt_core(const unsigned short* __restrict__ A,
                                             const unsigned short* __restrict__ Bm,
                                             unsigned short* As, unsigned short* Bs,
                                             int m0, int n0, int K, f32x4 acc[4][4]) {
  const int t = threadIdx.x;
  const int w = t >> 6;
  const int lr = t & 15;
  const int lg = (t & 63) >> 4;
  const int wm = (w >> 1) * 64;
  const int wn = (w & 1) * 64;

  const unsigned short* Ag0 = A + (size_t)(m0 + (t >> 2)) * K + (t & 3) * 8;
  const unsigned short* Ag1 = Ag0 + (size_t)64 * K;
  const unsigned short* Bg0 = Bm + (size_t)(n0 + (t >> 2)) * K + (t & 3) * 8;
  const unsigned short* Bg1 = Bg0 + (size_t)64 * K;
  char* AsB = (char*)As + (w * 64) * 16;
  char* BsB = (char*)Bs + (w * 64) * 16;

#pragma unroll
  for (int i = 0; i < 4; ++i)
#pragma unroll
    for (int j = 0; j < 4; ++j)
      acc[i][j] = (f32x4){0.f, 0.f, 0.f, 0.f};

  for (int kt = 0; kt < K; kt += 32) {
    lds16(Ag0 + kt, AsB);
    lds16(Ag1 + kt, AsB + 256 * 16);
    lds16(Bg0 + kt, BsB);
    lds16(Bg1 + kt, BsB + 256 * 16);
    __syncthreads();
    bf16x8 af[4], bf[4];
#pragma unroll
    for (int i = 0; i < 4; ++i)
      af[i] = *(const bf16x8*)(As + (wm + i * 16 + lr) * 32 + lg * 8);
#pragma unroll
    for (int j = 0; j < 4; ++j)
      bf[j] = *(const bf16x8*)(Bs + (wn + j * 16 + lr) * 32 + lg * 8);
#pragma unroll
    for (int i = 0; i < 4; ++i)
#pragma unroll
      for (int j = 0; j < 4; ++j)
        acc[i][j] = __builtin_amdgcn_mfma_f32_16x16x32_bf16(af[i], bf[j], acc[i][j], 0, 0, 0);
    __syncthreads();
  }
}

// ---------------- fused QKV projection ----------------
// X[8192,2048] @ Wqkv[6144,2048]^T + bias.
// Q,K written [b,h,s,d]; V written TRANSPOSED [b,h,d,s] for MFMA PV staging.
__global__ __launch_bounds__(256, 2)
void gemm_qkv(const unsigned short* __restrict__ X,
              const unsigned short* __restrict__ W,
              const float* __restrict__ bq,
              const float* __restrict__ bk,
              const float* __restrict__ bv,
              unsigned short* __restrict__ Qb,
              unsigned short* __restrict__ Kb,
              unsigned short* __restrict__ Vb) {
  __shared__ __align__(16) unsigned short As[128 * 32];
  __shared__ __align__(16) unsigned short Bs[128 * 32];
  const int m0 = blockIdx.y * 128;
  const int n0 = blockIdx.x * 128;  // 0..6143
  f32x4 acc[4][4];
  gemm_bt_core(X, W, As, Bs, m0, n0, EE, acc);

  const int t = threadIdx.x;
  const int w = t >> 6;
  const int lr = t & 15;
  const int lg = (t & 63) >> 4;
  const int wm = (w >> 1) * 64;
  const int wn = (w & 1) * 64;

  const int region = n0 >> 11;  // block-uniform: 0=Q 1=K 2=V
  unsigned short* Dst = (region == 0) ? Qb : (region == 1) ? Kb : Vb;
  const float* bp = (region == 0) ? bq : (region == 1) ? bk : bv;

  if (region == 2) {
    // V transposed: Vt[b][h][hd][s]
#pragma unroll
    for (int i = 0; i < 4; ++i) {
      const int row0 = m0 + wm + i * 16 + lg * 4;  // b*S + s, s%4==0
      const int b = row0 >> 11;
      const int s = row0 & 2047;
#pragma unroll
      for (int j = 0; j < 4; ++j) {
        const int c = (n0 + wn + j * 16 + lr) & 2047;
        const float bias = bp[c];
        const int h = c >> 7, hd = c & 127;
        const size_t base = ((size_t)(b * HH + h) * HD + hd) * SS + s;
#pragma unroll
        for (int re = 0; re < 4; ++re)
          Dst[base + re] = f2bf(acc[i][j][re] + bias);
      }
    }
  } else {
#pragma unroll
    for (int i = 0; i < 4; ++i) {
      const int row0 = m0 + wm + i * 16 + lg * 4;
      const int b = row0 >> 11;
      const int s = row0 & 2047;
#pragma unroll
      for (int j = 0; j < 4; ++j) {
        const int c = (n0 + wn + j * 16 + lr) & 2047;
        const float bias = bp[c];
        const int h = c >> 7, hd = c & 127;
        const size_t base = ((size_t)(b * HH + h) * SS + s) * HD + hd;
#pragma unroll
        for (int re = 0; re < 4; ++re)
          Dst[base + (size_t)re * HD] = f2bf(acc[i][j][re] + bias);
      }
    }
  }
}

// ---------------- output projection (f32 output!) ----------------
__global__ __launch_bounds__(256, 2)
void gemm_out(const unsigned short* __restrict__ A,
              const unsigned short* __restrict__ W,
              const float* __restrict__ bo,
              float* __restrict__ Out) {
  __shared__ __align__(16) unsigned short As[128 * 32];
  __shared__ __align__(16) unsigned short Bs[128 * 32];
  const int m0 = blockIdx.y * 128;
  const int n0 = blockIdx.x * 128;
  f32x4 acc[4][4];
  gemm_bt_core(A, W, As, Bs, m0, n0, EE, acc);

  const int t = threadIdx.x;
  const int w = t >> 6;
  const int lr = t & 15;
  const int lg = (t & 63) >> 4;
  const int wm = (w >> 1) * 64;
  const int wn = (w & 1) * 64;

#pragma unroll
  for (int i = 0; i < 4; ++i) {
    const int row0 = m0 + wm + i * 16 + lg * 4;
#pragma unroll
    for (int j = 0; j < 4; ++j) {
      const int col = n0 + wn + j * 16 + lr;
      const float bias = bo[col];
#pragma unroll
      for (int re = 0; re < 4; ++re)
        Out[(size_t)(row0 + re) * EE + col] = acc[i][j][re] + bias;
    }
  }
}

// ---------------- MFMA flash attention ----------------
// Block = 128 q-rows of one head (4 waves x 32 q). Loop over KV tiles of 64.
// Swapped QK^T: St = mfma(K_frag, Q_frag) -> St[k][q], so softmax reduction
// over k is in-lane (regs) + shfl_xor(16/32). P packed 4 consecutive-k bf16
// per ds_write_b64 into per-wave LDS. PV: O^T = mfma(Vt_frag, P_frag) with
// V pre-transposed globally ([b,h,d,s]) and staged like K.
// All LDS tiles XOR-swizzled: 16B chunk index ^= (row&7) (applied via
// pre-swizzled global source for global_load_lds; same XOR on reads).
__global__ __launch_bounds__(256, 2)
void attn_mfma(const unsigned short* __restrict__ Qb,
               const unsigned short* __restrict__ Kb,
               const unsigned short* __restrict__ Vtb,
               unsigned short* __restrict__ At) {
  __shared__ __align__(16) char lds[49152];
  char* Ks = lds;           // 16 KiB: K[64][128] bf16, swizzled
  char* Vs = lds + 16384;   // 16 KiB: Vt[128][64] bf16, swizzled
  const int t = threadIdx.x;
  const int w = t >> 6;
  const int ln = t & 63;
  const int lr = ln & 15;
  const int lg = ln >> 4;
  char* Ps = lds + 32768 + w * 4096;  // per-wave P[32][64] bf16, swizzled

  const int bh = blockIdx.y;
  const int qw = blockIdx.x * 128 + w * 32;  // wave's q base within head

  const unsigned short* Qh = Qb + (size_t)bh * SS * HD;
  const unsigned short* Kh = Kb + (size_t)bh * SS * HD;
  const unsigned short* Vh = Vtb + (size_t)bh * HD * SS;  // [d][s]

  // Q fragments (B-operand): q = qw + qi*16 + lr, d = ds*32 + lg*8 + 0..7
  bf16x8 qfr[2][4];
#pragma unroll
  for (int qi = 0; qi < 2; ++qi)
#pragma unroll
    for (int ds = 0; ds < 4; ++ds)
      qfr[qi][ds] = *(const bf16x8*)(Qh + (size_t)(qw + qi * 16 + lr) * HD + ds * 32 + lg * 8);

  // O^T accumulator: acc[df][qi] holds O[q = qi*16+lr][d = df*16 + 4*lg + re]
  f32x4 acc[8][2];
#pragma unroll
  for (int df = 0; df < 8; ++df)
#pragma unroll
    for (int qi = 0; qi < 2; ++qi)
      acc[df][qi] = (f32x4){0.f, 0.f, 0.f, 0.f};
  float mrun[2] = {-1e30f, -1e30f};
  float lsum[2] = {0.f, 0.f};  // per-lane partial (this lane's k-subset)

  for (int kt = 0; kt < SS; kt += 64) {
    // --- stage K tile (rows kt..kt+63): LDS chunk c holds
    //     K[row=c>>4][8 elems at gch*8], gch = (c&15)^(row&7)
#pragma unroll
    for (int i = 0; i < 4; ++i) {
      const int c = i * 256 + w * 64 + ln;
      const int row = c >> 4;
      const int gch = (c & 15) ^ (row & 7);
      lds16(Kh + (size_t)(kt + row) * HD + gch * 8, Ks + (i * 256 + w * 64) * 16);
    }
    // --- stage Vt tile (Vt[d][kt..kt+63]): chunk c holds
    //     Vt[d=c>>3][8 elems at kc*8], kc = (c&7)^(d&7)
#pragma unroll
    for (int i = 0; i < 4; ++i) {
      const int c = i * 256 + w * 64 + ln;
      const int d = c >> 3;
      const int kc = (c & 7) ^ (d & 7);
      lds16(Vh + (size_t)d * SS + kt + kc * 8, Vs + (i * 256 + w * 64) * 16);
    }
    __syncthreads();

    // --- QK^T (swapped): St[k = kf*16 + 4*lg + re][q = qi*16 + lr]
    f32x4 st[4][2];
#pragma unroll
    for (int kf = 0; kf < 4; ++kf) {
#pragma unroll
      for (int qi = 0; qi < 2; ++qi) st[kf][qi] = (f32x4){0.f, 0.f, 0.f, 0.f};
#pragma unroll
      for (int ds = 0; ds < 4; ++ds) {
        const int krow = kf * 16 + lr;
        bf16x8 kfr = *(const bf16x8*)(Ks + krow * 256 + (((ds * 4 + lg) ^ (krow & 7)) * 16));
#pragma unroll
        for (int qi = 0; qi < 2; ++qi)
          st[kf][qi] = __builtin_amdgcn_mfma_f32_16x16x32_bf16(kfr, qfr[qi][ds], st[kf][qi], 0, 0, 0);
      }
    }

    // --- online softmax (scale folded into exp arg)
#pragma unroll
    for (int qi = 0; qi < 2; ++qi) {
      float tm = st[0][qi][0];
#pragma unroll
      for (int kf = 0; kf < 4; ++kf)
#pragma unroll
        for (int r = 0; r < 4; ++r) tm = fmaxf(tm, st[kf][qi][r]);
      tm = fmaxf(tm, __shfl_xor(tm, 16, 64));
      tm = fmaxf(tm, __shfl_xor(tm, 32, 64));
      const float mnew = fmaxf(mrun[qi], tm);
      const float alpha = __expf((mrun[qi] - mnew) * SCALE);
      mrun[qi] = mnew;
      float rs = 0.f;
      const int qrow = qi * 16 + lr;
#pragma unroll
      for (int kf = 0; kf < 4; ++kf) {
        const float p0 = __expf((st[kf][qi][0] - mnew) * SCALE);
        const float p1 = __expf((st[kf][qi][1] - mnew) * SCALE);
        const float p2 = __expf((st[kf][qi][2] - mnew) * SCALE);
        const float p3 = __expf((st[kf][qi][3] - mnew) * SCALE);
        rs += (p0 + p1) + (p2 + p3);
        ushort4 pk;
        pk.x = f2bf(p0); pk.y = f2bf(p1); pk.z = f2bf(p2); pk.w = f2bf(p3);
        const int k0 = kf * 16 + lg * 4;  // 4 consecutive k
        *(ushort4*)(Ps + qrow * 128 + (((k0 >> 3) ^ (qrow & 7)) * 16) + (k0 & 7) * 2) = pk;
      }
      lsum[qi] = lsum[qi] * alpha + rs;
#pragma unroll
      for (int df = 0; df < 8; ++df) {
        acc[df][qi][0] *= alpha; acc[df][qi][1] *= alpha;
        acc[df][qi][2] *= alpha; acc[df][qi][3] *= alpha;
      }
    }

    // --- PV: O^T[d][q] += Vt x P (ds-write->read ordering within wave)
    bf16x8 pf[2][2];
#pragma unroll
    for (int ks = 0; ks < 2; ++ks)
#pragma unroll
      for (int qi = 0; qi < 2; ++qi) {
        const int qrow = qi * 16 + lr;
        pf[ks][qi] = *(const bf16x8*)(Ps + qrow * 128 + (((ks * 4 + lg) ^ (qrow & 7)) * 16));
      }
#pragma unroll
    for (int df = 0; df < 8; ++df) {
#pragma unroll
      for (int ks = 0; ks < 2; ++ks) {
        const int drow = df * 16 + lr;
        bf16x8 vfr = *(const bf16x8*)(Vs + drow * 128 + (((ks * 4 + lg) ^ (drow & 7)) * 16));
#pragma unroll
        for (int qi = 0; qi < 2; ++qi)
          acc[df][qi] = __builtin_amdgcn_mfma_f32_16x16x32_bf16(vfr, pf[ks][qi], acc[df][qi], 0, 0, 0);
      }
    }
    __syncthreads();
  }

  // --- finalize: cross-lane l reduce, divide, store bf16
  const int b = bh >> 4, h = bh & 15;
#pragma unroll
  for (int qi = 0; qi < 2; ++qi) {
    float l = lsum[qi];
    l += __shfl_xor(l, 16, 64);
    l += __shfl_xor(l, 32, 64);
    const float rl = 1.0f / l;
    const int s = qw + qi * 16 + lr;
    unsigned short* orow = At + ((size_t)(b * SS + s)) * EE + h * HD;
#pragma unroll
    for (int df = 0; df < 8; ++df)
#pragma unroll
      for (int r = 0; r < 4; ++r)
        orow[df * 16 + lg * 4 + r] = f2bf(acc[df][qi][r] * rl);
  }
}

// ---------------- launcher ----------------
extern "C" void kernel_launch(void* const* d_in, const int* in_sizes, int n_in,
                              void* d_out, int out_size, void* d_ws, size_t ws_size,
                              hipStream_t stream) {
  const float* QKV = (const float*)d_in[0];
  const float* Wq  = (const float*)d_in[1];
  const float* bq  = (const float*)d_in[2];
  const float* Wk  = (const float*)d_in[3];
  const float* bk  = (const float*)d_in[4];
  const float* Wv  = (const float*)d_in[5];
  const float* bv  = (const float*)d_in[6];
  const float* Wo  = (const float*)d_in[7];
  const float* bo  = (const float*)d_in[8];
  // d_in[9] = is_causal: masking is a no-op in the reference

  unsigned short* Xb = (unsigned short*)d_out;  // dead before gemm_out writes

  char* ws = (char*)d_ws;  // 152 MiB
  unsigned short* Wqkvb = (unsigned short*)(ws);                 // [  0, 24M)
  unsigned short* Qb    = (unsigned short*)(ws + ( 24u << 20));  // [ 24, 56M)
  unsigned short* Kb    = (unsigned short*)(ws + ( 56u << 20));  // [ 56, 88M)
  unsigned short* Vb    = (unsigned short*)(ws + ( 88u << 20));  // [ 88,120M) (transposed [b,h,d,s])
  unsigned short* At    = (unsigned short*)(ws + (120u << 20));  // [120,152M)
  unsigned short* Wob   = Wqkvb;  // reuses dead Wqkv region

  cvt_f32_bf16<<<dim3(16384), dim3(256), 0, stream>>>(QKV, Xb, 4194304);
  cvt_f32_bf16<<<dim3(4096), dim3(256), 0, stream>>>(Wq, Wqkvb, 1048576);
  cvt_f32_bf16<<<dim3(4096), dim3(256), 0, stream>>>(Wk, Wqkvb + 4194304, 1048576);
  cvt_f32_bf16<<<dim3(4096), dim3(256), 0, stream>>>(Wv, Wqkvb + 8388608, 1048576);

  gemm_qkv<<<dim3(48, 64), dim3(256), 0, stream>>>(Xb, Wqkvb, bq, bk, bv, Qb, Kb, Vb);
  attn_mfma<<<dim3(16, 64), dim3(256), 0, stream>>>(Qb, Kb, Vb, At);

  cvt_f32_bf16<<<dim3(4096), dim3(256), 0, stream>>>(Wo, Wob, 1048576);
  gemm_out<<<dim3(16, 64), dim3(256), 0, stream>>>(At, Wob, bo, (float*)d_out);
}

// Round 2
// 676.780 us; speedup vs baseline: 28.3822x; 1.0108x over previous
//
#include <hip/hip_runtime.h>
#include <stdint.h>

// Problem constants: B=4, S=2048, E=2048, H=16, HD=128
// Dtypes: inputs f32; OUTPUT f32. Intermediates bf16 (2% threshold).
#define BB 4
#define SS 2048
#define EE 2048
#define HH 16
#define HD 128
// SCALE * log2(e): folded into Q at the projection epilogue so attention
// softmax is pure exp2 (saves a v_mul per score element).
#define QSCALE 0.1275174490044696f

typedef __attribute__((ext_vector_type(8))) short bf16x8;
typedef __attribute__((ext_vector_type(4))) float f32x4;

__device__ __forceinline__ unsigned short f2bf(float f) {
  union { float f; unsigned u; } v;
  v.f = f;
  unsigned r = (v.u + 0x7fffu + ((v.u >> 16) & 1u)) >> 16;
  return (unsigned short)r;
}
__device__ __forceinline__ float bf2f(unsigned short u) {
  union { unsigned u; float f; } v;
  v.u = ((unsigned)u) << 16;
  return v.f;
}

// async global->LDS, 16B per lane. LDS dest = wave-uniform base + lane*16.
__device__ __forceinline__ void lds16(const void* g, void* l) {
  __builtin_amdgcn_global_load_lds(
      (__attribute__((address_space(1))) void*)(uintptr_t)g,
      (__attribute__((address_space(3))) void*)(uintptr_t)l,
      16, 0, 0);
}

// ---------------- fp32 -> bf16 conversion ----------------
__global__ void cvt_f32_bf16(const float* __restrict__ src,
                             unsigned short* __restrict__ dst, int n4) {
  int i = blockIdx.x * blockDim.x + threadIdx.x;
  if (i >= n4) return;
  float4 v = ((const float4*)src)[i];
  ushort4 o;
  o.x = f2bf(v.x); o.y = f2bf(v.y); o.z = f2bf(v.z); o.w = f2bf(v.w);
  ((ushort4*)dst)[i] = o;
}

// 3 weight matrices in one launch (blockIdx.y selects).
__global__ void cvt_w3(const float* __restrict__ Wq,
                       const float* __restrict__ Wk,
                       const float* __restrict__ Wv,
                       unsigned short* __restrict__ dst, int n4each) {
  const int which = blockIdx.y;
  const float* src = (which == 0) ? Wq : (which == 1) ? Wk : Wv;
  unsigned short* d = dst + (size_t)which * 4194304;
  int i = blockIdx.x * blockDim.x + threadIdx.x;
  if (i >= n4each) return;
  float4 v = ((const float4*)src)[i];
  ushort4 o;
  o.x = f2bf(v.x); o.y = f2bf(v.y); o.z = f2bf(v.z); o.w = f2bf(v.w);
  ((ushort4*)d)[i] = o;
}

// ---------------- m97-style bt-GEMM core ----------------
__device__ __forceinline__ void gemm_bt_core(const unsigned short* __restrict__ A,
                                             const unsigned short* __restrict__ Bm,
                                             unsigned short* As, unsigned short* Bs,
                                             int m0, int n0, int K, f32x4 acc[4][4]) {
  const int t = threadIdx.x;
  const int w = t >> 6;
  const int lr = t & 15;
  const int lg = (t & 63) >> 4;
  const int wm = (w >> 1) * 64;
  const int wn = (w & 1) * 64;

  const unsigned short* Ag0 = A + (size_t)(m0 + (t >> 2)) * K + (t & 3) * 8;
  const unsigned short* Ag1 = Ag0 + (size_t)64 * K;
  const unsigned short* Bg0 = Bm + (size_t)(n0 + (t >> 2)) * K + (t & 3) * 8;
  const unsigned short* Bg1 = Bg0 + (size_t)64 * K;
  char* AsB = (char*)As + (w * 64) * 16;
  char* BsB = (char*)Bs + (w * 64) * 16;

#pragma unroll
  for (int i = 0; i < 4; ++i)
#pragma unroll
    for (int j = 0; j < 4; ++j)
      acc[i][j] = (f32x4){0.f, 0.f, 0.f, 0.f};

  for (int kt = 0; kt < K; kt += 32) {
    lds16(Ag0 + kt, AsB);
    lds16(Ag1 + kt, AsB + 256 * 16);
    lds16(Bg0 + kt, BsB);
    lds16(Bg1 + kt, BsB + 256 * 16);
    __syncthreads();
    bf16x8 af[4], bf[4];
#pragma unroll
    for (int i = 0; i < 4; ++i)
      af[i] = *(const bf16x8*)(As + (wm + i * 16 + lr) * 32 + lg * 8);
#pragma unroll
    for (int j = 0; j < 4; ++j)
      bf[j] = *(const bf16x8*)(Bs + (wn + j * 16 + lr) * 32 + lg * 8);
#pragma unroll
    for (int i = 0; i < 4; ++i)
#pragma unroll
      for (int j = 0; j < 4; ++j)
        acc[i][j] = __builtin_amdgcn_mfma_f32_16x16x32_bf16(af[i], bf[j], acc[i][j], 0, 0, 0);
    __syncthreads();
  }
}

// ---------------- fused QKV projection ----------------
// X[8192,2048] @ Wqkv[6144,2048]^T + bias.
// Q written PRE-SCALED by QSCALE (attention uses exp2 softmax).
// Q,K written [b,h,s,d]; V written TRANSPOSED [b,h,d,s] for MFMA PV staging.
__global__ __launch_bounds__(256, 2)
void gemm_qkv(const unsigned short* __restrict__ X,
              const unsigned short* __restrict__ W,
              const float* __restrict__ bq,
              const float* __restrict__ bk,
              const float* __restrict__ bv,
              unsigned short* __restrict__ Qb,
              unsigned short* __restrict__ Kb,
              unsigned short* __restrict__ Vb) {
  __shared__ __align__(16) unsigned short As[128 * 32];
  __shared__ __align__(16) unsigned short Bs[128 * 32];
  const int m0 = blockIdx.y * 128;
  const int n0 = blockIdx.x * 128;  // 0..6143
  f32x4 acc[4][4];
  gemm_bt_core(X, W, As, Bs, m0, n0, EE, acc);

  const int t = threadIdx.x;
  const int w = t >> 6;
  const int lr = t & 15;
  const int lg = (t & 63) >> 4;
  const int wm = (w >> 1) * 64;
  const int wn = (w & 1) * 64;

  const int region = n0 >> 11;  // block-uniform: 0=Q 1=K 2=V
  unsigned short* Dst = (region == 0) ? Qb : (region == 1) ? Kb : Vb;
  const float* bp = (region == 0) ? bq : (region == 1) ? bk : bv;

  if (region == 2) {
    // V transposed: Vt[b][h][hd][s]
#pragma unroll
    for (int i = 0; i < 4; ++i) {
      const int row0 = m0 + wm + i * 16 + lg * 4;  // b*S + s, s%4==0
      const int b = row0 >> 11;
      const int s = row0 & 2047;
#pragma unroll
      for (int j = 0; j < 4; ++j) {
        const int c = (n0 + wn + j * 16 + lr) & 2047;
        const float bias = bp[c];
        const int h = c >> 7, hd = c & 127;
        const size_t base = ((size_t)(b * HH + h) * HD + hd) * SS + s;
#pragma unroll
        for (int re = 0; re < 4; ++re)
          Dst[base + re] = f2bf(acc[i][j][re] + bias);
      }
    }
  } else {
    const float osc = (region == 0) ? QSCALE : 1.0f;
#pragma unroll
    for (int i = 0; i < 4; ++i) {
      const int row0 = m0 + wm + i * 16 + lg * 4;
      const int b = row0 >> 11;
      const int s = row0 & 2047;
#pragma unroll
      for (int j = 0; j < 4; ++j) {
        const int c = (n0 + wn + j * 16 + lr) & 2047;
        const float bias = bp[c];
        const int h = c >> 7, hd = c & 127;
        const size_t base = ((size_t)(b * HH + h) * SS + s) * HD + hd;
#pragma unroll
        for (int re = 0; re < 4; ++re)
          Dst[base + (size_t)re * HD] = f2bf((acc[i][j][re] + bias) * osc);
      }
    }
  }
}

// ---------------- output projection (f32 output!) ----------------
__global__ __launch_bounds__(256, 2)
void gemm_out(const unsigned short* __restrict__ A,
              const unsigned short* __restrict__ W,
              const float* __restrict__ bo,
              float* __restrict__ Out) {
  __shared__ __align__(16) unsigned short As[128 * 32];
  __shared__ __align__(16) unsigned short Bs[128 * 32];
  const int m0 = blockIdx.y * 128;
  const int n0 = blockIdx.x * 128;
  f32x4 acc[4][4];
  gemm_bt_core(A, W, As, Bs, m0, n0, EE, acc);

  const int t = threadIdx.x;
  const int w = t >> 6;
  const int lr = t & 15;
  const int lg = (t & 63) >> 4;
  const int wm = (w >> 1) * 64;
  const int wn = (w & 1) * 64;

#pragma unroll
  for (int i = 0; i < 4; ++i) {
    const int row0 = m0 + wm + i * 16 + lg * 4;
#pragma unroll
    for (int j = 0; j < 4; ++j) {
      const int col = n0 + wn + j * 16 + lr;
      const float bias = bo[col];
#pragma unroll
      for (int re = 0; re < 4; ++re)
        Out[(size_t)(row0 + re) * EE + col] = acc[i][j][re] + bias;
    }
  }
}

// ---------------- MFMA flash attention (v2: dbuf + setprio + defer-max) ----
// Block = 128 q-rows of one head (4 waves x 32 q). KV tiles of 64.
// v2 changes vs v1:
//  - K/V LDS double-buffered: next tile's global_load_lds issued BEFORE
//    current tile's compute; ONE __syncthreads per tile (its implicit
//    vmcnt(0) lands after ~1000cy of compute -> latency hidden). [T14/T3-min]
//  - s_setprio(1) around both MFMA clusters. [T5]
//  - Q pre-scaled by SCALE*log2e at projection -> softmax is pure exp2.
//  - defer-max (THR=8, exp2 units): wave-uniform __all skip of O-rescale. [T13]
__global__ __launch_bounds__(256, 2)
void attn_mfma(const unsigned short* __restrict__ Qb,
               const unsigned short* __restrict__ Kb,
               const unsigned short* __restrict__ Vtb,
               unsigned short* __restrict__ At) {
  // [0,32K) buf0 {K 16K, Vt 16K}; [32K,64K) buf1; [64K,80K) P (4K/wave)
  __shared__ __align__(16) char lds[81920];
  const int t = threadIdx.x;
  const int w = t >> 6;
  const int ln = t & 63;
  const int lr = ln & 15;
  const int lg = ln >> 4;
  char* Ps = lds + 65536 + w * 4096;

  const int bh = blockIdx.y;
  const int qw = blockIdx.x * 128 + w * 32;  // wave's q base within head

  const unsigned short* Qh = Qb + (size_t)bh * SS * HD;
  const unsigned short* Kh = Kb + (size_t)bh * SS * HD;
  const unsigned short* Vh = Vtb + (size_t)bh * HD * SS;  // [d][s]

  // Q fragments (B-operand): q = qw + qi*16 + lr, d = ds*32 + lg*8 + 0..7
  bf16x8 qfr[2][4];
#pragma unroll
  for (int qi = 0; qi < 2; ++qi)
#pragma unroll
    for (int ds = 0; ds < 4; ++ds)
      qfr[qi][ds] = *(const bf16x8*)(Qh + (size_t)(qw + qi * 16 + lr) * HD + ds * 32 + lg * 8);

  // O^T accumulator: acc[df][qi] holds O[q = qi*16+lr][d = df*16 + 4*lg + re]
  f32x4 acc[8][2];
#pragma unroll
  for (int df = 0; df < 8; ++df)
#pragma unroll
    for (int qi = 0; qi < 2; ++qi)
      acc[df][qi] = (f32x4){0.f, 0.f, 0.f, 0.f};
  float mrun[2] = {-3.0e38f, -3.0e38f};
  float lsum[2] = {0.f, 0.f};  // per-lane partial (this lane's k-subset)

  // Stage tile at key offset kt into buffer `buf`. K: chunk c holds
  // K[row=c>>4][8 elems at gch*8], gch=(c&15)^(row&7). Vt: chunk c holds
  // Vt[d=c>>3][8 elems at kc*8], kc=(c&7)^(d&7). (XOR pre-swizzled source.)
#define STAGE_KV(kt, buf)                                                      \
  do {                                                                         \
    char* Kd = lds + (buf) * 32768;                                            \
    char* Vd = Kd + 16384;                                                     \
    _Pragma("unroll") for (int i = 0; i < 4; ++i) {                            \
      const int c = i * 256 + w * 64 + ln;                                     \
      const int row = c >> 4;                                                  \
      const int gch = (c & 15) ^ (row & 7);                                    \
      lds16(Kh + (size_t)((kt) + row) * HD + gch * 8,                          \
            Kd + (i * 256 + w * 64) * 16);                                     \
    }                                                                          \
    _Pragma("unroll") for (int i = 0; i < 4; ++i) {                            \
      const int c = i * 256 + w * 64 + ln;                                     \
      const int d = c >> 3;                                                    \
      const int kc = (c & 7) ^ (d & 7);                                        \
      lds16(Vh + (size_t)d * SS + (kt) + kc * 8,                               \
            Vd + (i * 256 + w * 64) * 16);                                     \
    }                                                                          \
  } while (0)

  STAGE_KV(0, 0);
  __syncthreads();  // implicit vmcnt(0): tile 0 landed

  int cur = 0;
  for (int kt = 0; kt < SS; kt += 64) {
    // Prefetch next tile into the other buffer (reads of it finished at the
    // previous iteration's end-barrier) -- latency hides under compute.
    if (kt + 64 < SS) STAGE_KV(kt + 64, cur ^ 1);

    char* Ks = lds + cur * 32768;
    char* Vs = Ks + 16384;

    // --- QK^T (swapped): St[k = kf*16 + 4*lg + re][q = qi*16 + lr]
    f32x4 st[4][2];
    __builtin_amdgcn_s_setprio(1);
#pragma unroll
    for (int kf = 0; kf < 4; ++kf) {
#pragma unroll
      for (int qi = 0; qi < 2; ++qi) st[kf][qi] = (f32x4){0.f, 0.f, 0.f, 0.f};
#pragma unroll
      for (int ds = 0; ds < 4; ++ds) {
        const int krow = kf * 16 + lr;
        bf16x8 kfr = *(const bf16x8*)(Ks + krow * 256 + (((ds * 4 + lg) ^ (krow & 7)) * 16));
#pragma unroll
        for (int qi = 0; qi < 2; ++qi)
          st[kf][qi] = __builtin_amdgcn_mfma_f32_16x16x32_bf16(kfr, qfr[qi][ds], st[kf][qi], 0, 0, 0);
      }
    }
    __builtin_amdgcn_s_setprio(0);

    // --- online softmax (Q pre-scaled: scores already in log2 units)
#pragma unroll
    for (int qi = 0; qi < 2; ++qi) {
      float tm = st[0][qi][0];
#pragma unroll
      for (int kf = 0; kf < 4; ++kf)
#pragma unroll
        for (int r = 0; r < 4; ++r) tm = fmaxf(tm, st[kf][qi][r]);
      tm = fmaxf(tm, __shfl_xor(tm, 16, 64));
      tm = fmaxf(tm, __shfl_xor(tm, 32, 64));
      // defer-max: only rescale when some row's max grew by > 8 (exp2 units;
      // P then bounded by 2^8, fine in bf16). Wave-uniform branch.
      if (!__all(tm <= mrun[qi] + 8.0f)) {
        const float mnew = fmaxf(mrun[qi], tm);
        const float alpha = __builtin_exp2f(mrun[qi] - mnew);
        mrun[qi] = mnew;
        lsum[qi] *= alpha;
#pragma unroll
        for (int df = 0; df < 8; ++df) {
          acc[df][qi][0] *= alpha; acc[df][qi][1] *= alpha;
          acc[df][qi][2] *= alpha; acc[df][qi][3] *= alpha;
        }
      }
      const float mcur = mrun[qi];
      float rs = 0.f;
      const int qrow = qi * 16 + lr;
#pragma unroll
      for (int kf = 0; kf < 4; ++kf) {
        const float p0 = __builtin_exp2f(st[kf][qi][0] - mcur);
        const float p1 = __builtin_exp2f(st[kf][qi][1] - mcur);
        const float p2 = __builtin_exp2f(st[kf][qi][2] - mcur);
        const float p3 = __builtin_exp2f(st[kf][qi][3] - mcur);
        rs += (p0 + p1) + (p2 + p3);
        ushort4 pk;
        pk.x = f2bf(p0); pk.y = f2bf(p1); pk.z = f2bf(p2); pk.w = f2bf(p3);
        const int k0 = kf * 16 + lg * 4;  // 4 consecutive k
        *(ushort4*)(Ps + qrow * 128 + (((k0 >> 3) ^ (qrow & 7)) * 16) + (k0 & 7) * 2) = pk;
      }
      lsum[qi] += rs;
    }

    // --- PV: O^T[d][q] += Vt x P (per-wave ds write->read, lgkmcnt-ordered)
    bf16x8 pf[2][2];
#pragma unroll
    for (int ks = 0; ks < 2; ++ks)
#pragma unroll
      for (int qi = 0; qi < 2; ++qi) {
        const int qrow = qi * 16 + lr;
        pf[ks][qi] = *(const bf16x8*)(Ps + qrow * 128 + (((ks * 4 + lg) ^ (qrow & 7)) * 16));
      }
    __builtin_amdgcn_s_setprio(1);
#pragma unroll
    for (int df = 0; df < 8; ++df) {
#pragma unroll
      for (int ks = 0; ks < 2; ++ks) {
        const int drow = df * 16 + lr;
        bf16x8 vfr = *(const bf16x8*)(Vs + drow * 128 + (((ks * 4 + lg) ^ (drow & 7)) * 16));
#pragma unroll
        for (int qi = 0; qi < 2; ++qi)
          acc[df][qi] = __builtin_amdgcn_mfma_f32_16x16x32_bf16(vfr, pf[ks][qi], acc[df][qi], 0, 0, 0);
      }
    }
    __builtin_amdgcn_s_setprio(0);

    // One barrier per tile: implicit vmcnt(0) guarantees next tile landed;
    // also fences this buffer's reads before it's re-staged next iteration.
    __syncthreads();
    cur ^= 1;
  }

  // --- finalize: cross-lane l reduce, divide, store bf16
  const int b = bh >> 4, h = bh & 15;
#pragma unroll
  for (int qi = 0; qi < 2; ++qi) {
    float l = lsum[qi];
    l += __shfl_xor(l, 16, 64);
    l += __shfl_xor(l, 32, 64);
    const float rl = 1.0f / l;
    const int s = qw + qi * 16 + lr;
    unsigned short* orow = At + ((size_t)(b * SS + s)) * EE + h * HD;
#pragma unroll
    for (int df = 0; df < 8; ++df)
#pragma unroll
      for (int r = 0; r < 4; ++r)
        orow[df * 16 + lg * 4 + r] = f2bf(acc[df][qi][r] * rl);
  }
}

// ---------------- launcher ----------------
extern "C" void kernel_launch(void* const* d_in, const int* in_sizes, int n_in,
                              void* d_out, int out_size, void* d_ws, size_t ws_size,
                              hipStream_t stream) {
  const float* QKV = (const float*)d_in[0];
  const float* Wq  = (const float*)d_in[1];
  const float* bq  = (const float*)d_in[2];
  const float* Wk  = (const float*)d_in[3];
  const float* bk  = (const float*)d_in[4];
  const float* Wv  = (const float*)d_in[5];
  const float* bv  = (const float*)d_in[6];
  const float* Wo  = (const float*)d_in[7];
  const float* bo  = (const float*)d_in[8];
  // d_in[9] = is_causal: masking is a no-op in the reference

  unsigned short* Xb = (unsigned short*)d_out;  // dead before gemm_out writes

  char* ws = (char*)d_ws;  // 152 MiB
  unsigned short* Wqkvb = (unsigned short*)(ws);                 // [  0, 24M)
  unsigned short* Qb    = (unsigned short*)(ws + ( 24u << 20));  // [ 24, 56M)
  unsigned short* Kb    = (unsigned short*)(ws + ( 56u << 20));  // [ 56, 88M)
  unsigned short* Vb    = (unsigned short*)(ws + ( 88u << 20));  // [ 88,120M) (transposed [b,h,d,s])
  unsigned short* At    = (unsigned short*)(ws + (120u << 20));  // [120,152M)
  unsigned short* Wob   = Wqkvb;  // reuses dead Wqkv region

  cvt_f32_bf16<<<dim3(16384), dim3(256), 0, stream>>>(QKV, Xb, 4194304);
  cvt_w3<<<dim3(4096, 3), dim3(256), 0, stream>>>(Wq, Wk, Wv, Wqkvb, 1048576);

  gemm_qkv<<<dim3(48, 64), dim3(256), 0, stream>>>(Xb, Wqkvb, bq, bk, bv, Qb, Kb, Vb);
  attn_mfma<<<dim3(16, 64), dim3(256), 0, stream>>>(Qb, Kb, Vb, At);

  cvt_f32_bf16<<<dim3(4096), dim3(256), 0, stream>>>(Wo, Wob, 1048576);
  gemm_out<<<dim3(16, 64), dim3(256), 0, stream>>>(At, Wob, bo, (float*)d_out);
}

// Round 5
// 614.310 us; speedup vs baseline: 31.2684x; 1.1017x over previous
//
#include <hip/hip_runtime.h>
#include <stdint.h>

// Problem constants: B=4, S=2048, E=2048, H=16, HD=128
// Dtypes: inputs f32; OUTPUT f32. Intermediates bf16 (2% threshold).
#define BB 4
#define SS 2048
#define EE 2048
#define HH 16
#define HD 128
// SCALE * log2(e): folded into Q at the projection epilogue so attention
// softmax is pure exp2 (saves a v_mul per score element).
#define QSCALE 0.1275174490044696f

typedef __attribute__((ext_vector_type(8))) short bf16x8;
typedef __attribute__((ext_vector_type(4))) float f32x4;

__device__ __forceinline__ unsigned short f2bf(float f) {
  union { float f; unsigned u; } v;
  v.f = f;
  unsigned r = (v.u + 0x7fffu + ((v.u >> 16) & 1u)) >> 16;
  return (unsigned short)r;
}

// async global->LDS, 16B per lane. LDS dest = wave-uniform base + lane*16.
__device__ __forceinline__ void lds16(const void* g, void* l) {
  __builtin_amdgcn_global_load_lds(
      (__attribute__((address_space(1))) void*)(uintptr_t)g,
      (__attribute__((address_space(3))) void*)(uintptr_t)l,
      16, 0, 0);
}

// ---------------- fp32 -> bf16 conversion ----------------
__global__ void cvt_f32_bf16(const float* __restrict__ src,
                             unsigned short* __restrict__ dst, int n4) {
  int i = blockIdx.x * blockDim.x + threadIdx.x;
  if (i >= n4) return;
  float4 v = ((const float4*)src)[i];
  ushort4 o;
  o.x = f2bf(v.x); o.y = f2bf(v.y); o.z = f2bf(v.z); o.w = f2bf(v.w);
  ((ushort4*)dst)[i] = o;
}

// 3 weight matrices in one launch (blockIdx.y selects).
__global__ void cvt_w3(const float* __restrict__ Wq,
                       const float* __restrict__ Wk,
                       const float* __restrict__ Wv,
                       unsigned short* __restrict__ dst, int n4each) {
  const int which = blockIdx.y;
  const float* src = (which == 0) ? Wq : (which == 1) ? Wk : Wv;
  unsigned short* d = dst + (size_t)which * 4194304;
  int i = blockIdx.x * blockDim.x + threadIdx.x;
  if (i >= n4each) return;
  float4 v = ((const float4*)src)[i];
  ushort4 o;
  o.x = f2bf(v.x); o.y = f2bf(v.y); o.z = f2bf(v.z); o.w = f2bf(v.w);
  ((ushort4*)d)[i] = o;
}

// ---------------- 256x256 8-phase bt-GEMM core (m201 template) -----------
// C[256x256 tile] = A[m0:,:2048] @ Bm[n0:,:2048]^T, both K-major bf16.
// 512 threads = 8 waves (2M x 4N); per-wave output 128x64.
// LDS 128 KiB: 2 dbuf x { A: 2 halves [128][64], B: 2 halves [128][64] }.
// Swizzle: 16B chunk index c ^= (row&7), applied on the GLOBAL source of
// global_load_lds (linear LDS dest) and identically on ds_read (rule #21).
// Per K-tile: 4 phases (C-quadrants); each phase: {ds_read frags || stage
// one half-tile of tile t+1} -> s_barrier -> setprio(1) 16 MFMA setprio(0)
// -> s_barrier. SYNC DISCIPLINE: intra-tile barriers are raw s_barrier
// (both LDS buffers stable across them -> no memory-order requirement);
// the TILE-BOUNDARY barrier is __syncthreads() (true workgroup fence +
// implicit vmcnt(0) drain) so neither the new-buffer ds_reads nor the
// prefetch global_load_lds can be compiler-moved across the buffer handoff.
// AUDIT (r4->r5): barrier counts wave-uniform; all LDS/global addresses
// bounds-checked; no runtime-indexed local arrays. Resubmitted unchanged —
// r3/r4 "container failed" is attributed to infra (pushes took 900+s even
// in passing rounds; a data race would report passed:false, not kill the
// container).
__device__ __forceinline__ void gemm256_core(
    const unsigned short* __restrict__ A,
    const unsigned short* __restrict__ Bm,
    char* lds, int m0, int n0, f32x4 acc[8][4]) {
  const int t = threadIdx.x;
  const int w = t >> 6;
  const int ln = t & 63;
  const int lr = ln & 15;
  const int lg = ln >> 4;
  const int wr = w >> 2;   // 0..1: M half
  const int wc = w & 3;    // 0..3: N quarter

  // Staging: element offsets (32-bit) for {A-h0,A-h1,B-h0,B-h1} x {s0,s1}.
  // Chunk C = s*512 + w*64 + ln; row = C>>3 (within half), swizzled k-chunk
  // kch = (C&7) ^ (row&7); source row = (m0|n0) + h*128 + row.
  unsigned offs[4][2];
  int dof[4][2];  // wave-uniform LDS byte offset within buffer
#pragma unroll
  for (int h = 0; h < 2; ++h)
#pragma unroll
    for (int s = 0; s < 2; ++s) {
      const int C = s * 512 + w * 64 + ln;
      const int row = C >> 3;
      const int kch = (C & 7) ^ (row & 7);
      offs[h][s]     = (unsigned)(m0 + h * 128 + row) * EE + kch * 8;
      offs[2 + h][s] = (unsigned)(n0 + h * 128 + row) * EE + kch * 8;
      dof[h][s] = h * 16384 + (s * 512 + w * 64) * 16;
      dof[2 + h][s] = 32768 + h * 16384 + (s * 512 + w * 64) * 16;
    }

#pragma unroll
  for (int i = 0; i < 8; ++i)
#pragma unroll
    for (int j = 0; j < 4; ++j) acc[i][j] = (f32x4){0.f, 0.f, 0.f, 0.f};

  // Prologue: stage tile 0 into buf0; full drain + fence + publish.
#pragma unroll
  for (int q = 0; q < 4; ++q)
#pragma unroll
    for (int s = 0; s < 2; ++s)
      lds16(((q < 2) ? A : Bm) + offs[q][s], lds + dof[q][s]);
  __syncthreads();

  // Fragment read chunk columns (row&7 == lr&7 for all fragment rows).
  const int cc0 = lg ^ (lr & 7);        // ks=0
  const int cc1 = (4 + lg) ^ (lr & 7);  // ks=1
  const int brbase = (wc & 1) * 64;

  bf16x8 afr[4][2];      // current qm's A frags (reused across qn)
  bf16x8 bfr[2][2][2];   // both qn's B frags (live all 4 phases)
  int bufo = 0;
  for (int kt = 0; kt < EE; kt += 64) {
    char* cb = lds + bufo;
    char* pb = lds + (bufo ^ 65536);
    const char* Ard = cb + wr * 16384;
    const char* Brd = cb + 32768 + (wc >> 1) * 16384;
    const bool pre = (kt + 64 < EE);
#pragma unroll
    for (int ph = 0; ph < 4; ++ph) {
      const int qm = ph >> 1, qn = ph & 1;
      if (qn == 0) {  // (re)load A frags for this qm: 8 x ds_read_b128
#pragma unroll
        for (int i = 0; i < 4; ++i) {
          const int r = qm * 64 + i * 16 + lr;
          afr[i][0] = *(const bf16x8*)(Ard + r * 128 + cc0 * 16);
          afr[i][1] = *(const bf16x8*)(Ard + r * 128 + cc1 * 16);
        }
      }
      if (ph < 2) {  // load B frags for qn=ph: 4 x ds_read_b128
#pragma unroll
        for (int j = 0; j < 2; ++j) {
          const int r = brbase + ph * 32 + j * 16 + lr;
          bfr[ph][j][0] = *(const bf16x8*)(Brd + r * 128 + cc0 * 16);
          bfr[ph][j][1] = *(const bf16x8*)(Brd + r * 128 + cc1 * 16);
        }
      }
      if (pre) {  // stage half-tile `ph` of tile t+1 into other buffer
        lds16(((ph < 2) ? A : Bm) + (offs[ph][0] + (kt + 64)), pb + dof[ph][0]);
        lds16(((ph < 2) ? A : Bm) + (offs[ph][1] + (kt + 64)), pb + dof[ph][1]);
      }
      __builtin_amdgcn_s_barrier();
      __builtin_amdgcn_s_setprio(1);
#pragma unroll
      for (int i = 0; i < 4; ++i)
#pragma unroll
        for (int j = 0; j < 2; ++j) {
          acc[qm * 4 + i][qn * 2 + j] = __builtin_amdgcn_mfma_f32_16x16x32_bf16(
              afr[i][0], bfr[qn][j][0], acc[qm * 4 + i][qn * 2 + j], 0, 0, 0);
          acc[qm * 4 + i][qn * 2 + j] = __builtin_amdgcn_mfma_f32_16x16x32_bf16(
              afr[i][1], bfr[qn][j][1], acc[qm * 4 + i][qn * 2 + j], 0, 0, 0);
        }
      __builtin_amdgcn_s_setprio(0);
      if (ph < 3) {
        __builtin_amdgcn_s_barrier();  // intra-tile: buffers stable, no fence needed
      } else {
        __syncthreads();  // tile boundary: fence + vmcnt(0) drain + barrier
      }
    }
    bufo ^= 65536;
  }
}

// ---------------- fused QKV projection (256^2 tiles) ----------------
// X[8192,2048] @ Wqkv[6144,2048]^T + bias.
// Q written PRE-SCALED by QSCALE; Q,K [b,h,s,d]; V TRANSPOSED [b,h,d,s].
__global__ __launch_bounds__(512, 1)
void gemm_qkv(const unsigned short* __restrict__ X,
              const unsigned short* __restrict__ W,
              const float* __restrict__ bq,
              const float* __restrict__ bk,
              const float* __restrict__ bv,
              unsigned short* __restrict__ Qb,
              unsigned short* __restrict__ Kb,
              unsigned short* __restrict__ Vb) {
  __shared__ __align__(16) char lds[131072];
  const int m0 = blockIdx.y * 256;
  const int n0 = blockIdx.x * 256;  // 0..5888; region uniform (2048%256==0)
  f32x4 acc[8][4];
  gemm256_core(X, W, lds, m0, n0, acc);

  const int t = threadIdx.x;
  const int w = t >> 6;
  const int lr = t & 15;
  const int lg = (t & 63) >> 4;
  const int wrm = (w >> 2) * 128;
  const int wcn = (w & 3) * 64;

  const int region = n0 >> 11;  // 0=Q 1=K 2=V
  unsigned short* Dst = (region == 0) ? Qb : (region == 1) ? Kb : Vb;
  const float* bp = (region == 0) ? bq : (region == 1) ? bk : bv;

  if (region == 2) {
    // V transposed: Vt[b][h][hd][s]
#pragma unroll
    for (int mi = 0; mi < 8; ++mi) {
      const int row0 = m0 + wrm + mi * 16 + lg * 4;  // b*S + s, s%4==0
      const int b = row0 >> 11;
      const int s = row0 & 2047;
#pragma unroll
      for (int nj = 0; nj < 4; ++nj) {
        const int c = (n0 + wcn + nj * 16 + lr) & 2047;
        const float bias = bp[c];
        const int h = c >> 7, hd = c & 127;
        const size_t base = ((size_t)(b * HH + h) * HD + hd) * SS + s;
#pragma unroll
        for (int re = 0; re < 4; ++re)
          Dst[base + re] = f2bf(acc[mi][nj][re] + bias);
      }
    }
  } else {
    const float osc = (region == 0) ? QSCALE : 1.0f;
#pragma unroll
    for (int mi = 0; mi < 8; ++mi) {
      const int row0 = m0 + wrm + mi * 16 + lg * 4;
      const int b = row0 >> 11;
      const int s = row0 & 2047;
#pragma unroll
      for (int nj = 0; nj < 4; ++nj) {
        const int c = (n0 + wcn + nj * 16 + lr) & 2047;
        const float bias = bp[c];
        const int h = c >> 7, hd = c & 127;
        const size_t base = ((size_t)(b * HH + h) * SS + s) * HD + hd;
#pragma unroll
        for (int re = 0; re < 4; ++re)
          Dst[base + (size_t)re * HD] = f2bf((acc[mi][nj][re] + bias) * osc);
      }
    }
  }
}

// ---------------- output projection (256^2 tiles, f32 output!) -----------
__global__ __launch_bounds__(512, 1)
void gemm_out(const unsigned short* __restrict__ A,
              const unsigned short* __restrict__ W,
              const float* __restrict__ bo,
              float* __restrict__ Out) {
  __shared__ __align__(16) char lds[131072];
  const int m0 = blockIdx.y * 256;
  const int n0 = blockIdx.x * 256;
  f32x4 acc[8][4];
  gemm256_core(A, W, lds, m0, n0, acc);

  const int t = threadIdx.x;
  const int w = t >> 6;
  const int lr = t & 15;
  const int lg = (t & 63) >> 4;
  const int wrm = (w >> 2) * 128;
  const int wcn = (w & 3) * 64;

#pragma unroll
  for (int mi = 0; mi < 8; ++mi) {
    const int row0 = m0 + wrm + mi * 16 + lg * 4;
#pragma unroll
    for (int nj = 0; nj < 4; ++nj) {
      const int col = n0 + wcn + nj * 16 + lr;
      const float bias = bo[col];
#pragma unroll
      for (int re = 0; re < 4; ++re)
        Out[(size_t)(row0 + re) * EE + col] = acc[mi][nj][re] + bias;
    }
  }
}

// ---------------- MFMA flash attention (unchanged from r2, passed) --------
__global__ __launch_bounds__(256, 2)
void attn_mfma(const unsigned short* __restrict__ Qb,
               const unsigned short* __restrict__ Kb,
               const unsigned short* __restrict__ Vtb,
               unsigned short* __restrict__ At) {
  // [0,32K) buf0 {K 16K, Vt 16K}; [32K,64K) buf1; [64K,80K) P (4K/wave)
  __shared__ __align__(16) char lds[81920];
  const int t = threadIdx.x;
  const int w = t >> 6;
  const int ln = t & 63;
  const int lr = ln & 15;
  const int lg = ln >> 4;
  char* Ps = lds + 65536 + w * 4096;

  const int bh = blockIdx.y;
  const int qw = blockIdx.x * 128 + w * 32;  // wave's q base within head

  const unsigned short* Qh = Qb + (size_t)bh * SS * HD;
  const unsigned short* Kh = Kb + (size_t)bh * SS * HD;
  const unsigned short* Vh = Vtb + (size_t)bh * HD * SS;  // [d][s]

  // Q fragments (B-operand): q = qw + qi*16 + lr, d = ds*32 + lg*8 + 0..7
  bf16x8 qfr[2][4];
#pragma unroll
  for (int qi = 0; qi < 2; ++qi)
#pragma unroll
    for (int ds = 0; ds < 4; ++ds)
      qfr[qi][ds] = *(const bf16x8*)(Qh + (size_t)(qw + qi * 16 + lr) * HD + ds * 32 + lg * 8);

  // O^T accumulator: acc[df][qi] holds O[q = qi*16+lr][d = df*16 + 4*lg + re]
  f32x4 acc[8][2];
#pragma unroll
  for (int df = 0; df < 8; ++df)
#pragma unroll
    for (int qi = 0; qi < 2; ++qi)
      acc[df][qi] = (f32x4){0.f, 0.f, 0.f, 0.f};
  float mrun[2] = {-3.0e38f, -3.0e38f};
  float lsum[2] = {0.f, 0.f};  // per-lane partial (this lane's k-subset)

#define STAGE_KV(kt, buf)                                                      \
  do {                                                                         \
    char* Kd = lds + (buf) * 32768;                                            \
    char* Vd = Kd + 16384;                                                     \
    _Pragma("unroll") for (int i = 0; i < 4; ++i) {                            \
      const int c = i * 256 + w * 64 + ln;                                     \
      const int row = c >> 4;                                                  \
      const int gch = (c & 15) ^ (row & 7);                                    \
      lds16(Kh + (size_t)((kt) + row) * HD + gch * 8,                          \
            Kd + (i * 256 + w * 64) * 16);                                     \
    }                                                                          \
    _Pragma("unroll") for (int i = 0; i < 4; ++i) {                            \
      const int c = i * 256 + w * 64 + ln;                                     \
      const int d = c >> 3;                                                    \
      const int kc = (c & 7) ^ (d & 7);                                        \
      lds16(Vh + (size_t)d * SS + (kt) + kc * 8,                               \
            Vd + (i * 256 + w * 64) * 16);                                     \
    }                                                                          \
  } while (0)

  STAGE_KV(0, 0);
  __syncthreads();  // implicit vmcnt(0): tile 0 landed

  int cur = 0;
  for (int kt = 0; kt < SS; kt += 64) {
    if (kt + 64 < SS) STAGE_KV(kt + 64, cur ^ 1);

    char* Ks = lds + cur * 32768;
    char* Vs = Ks + 16384;

    // --- QK^T (swapped): St[k = kf*16 + 4*lg + re][q = qi*16 + lr]
    f32x4 st[4][2];
    __builtin_amdgcn_s_setprio(1);
#pragma unroll
    for (int kf = 0; kf < 4; ++kf) {
#pragma unroll
      for (int qi = 0; qi < 2; ++qi) st[kf][qi] = (f32x4){0.f, 0.f, 0.f, 0.f};
#pragma unroll
      for (int ds = 0; ds < 4; ++ds) {
        const int krow = kf * 16 + lr;
        bf16x8 kfr = *(const bf16x8*)(Ks + krow * 256 + (((ds * 4 + lg) ^ (krow & 7)) * 16));
#pragma unroll
        for (int qi = 0; qi < 2; ++qi)
          st[kf][qi] = __builtin_amdgcn_mfma_f32_16x16x32_bf16(kfr, qfr[qi][ds], st[kf][qi], 0, 0, 0);
      }
    }
    __builtin_amdgcn_s_setprio(0);

    // --- online softmax (Q pre-scaled: scores already in log2 units)
#pragma unroll
    for (int qi = 0; qi < 2; ++qi) {
      float tm = st[0][qi][0];
#pragma unroll
      for (int kf = 0; kf < 4; ++kf)
#pragma unroll
        for (int r = 0; r < 4; ++r) tm = fmaxf(tm, st[kf][qi][r]);
      tm = fmaxf(tm, __shfl_xor(tm, 16, 64));
      tm = fmaxf(tm, __shfl_xor(tm, 32, 64));
      if (!__all(tm <= mrun[qi] + 8.0f)) {
        const float mnew = fmaxf(mrun[qi], tm);
        const float alpha = __builtin_exp2f(mrun[qi] - mnew);
        mrun[qi] = mnew;
        lsum[qi] *= alpha;
#pragma unroll
        for (int df = 0; df < 8; ++df) {
          acc[df][qi][0] *= alpha; acc[df][qi][1] *= alpha;
          acc[df][qi][2] *= alpha; acc[df][qi][3] *= alpha;
        }
      }
      const float mcur = mrun[qi];
      float rs = 0.f;
      const int qrow = qi * 16 + lr;
#pragma unroll
      for (int kf = 0; kf < 4; ++kf) {
        const float p0 = __builtin_exp2f(st[kf][qi][0] - mcur);
        const float p1 = __builtin_exp2f(st[kf][qi][1] - mcur);
        const float p2 = __builtin_exp2f(st[kf][qi][2] - mcur);
        const float p3 = __builtin_exp2f(st[kf][qi][3] - mcur);
        rs += (p0 + p1) + (p2 + p3);
        ushort4 pk;
        pk.x = f2bf(p0); pk.y = f2bf(p1); pk.z = f2bf(p2); pk.w = f2bf(p3);
        const int k0 = kf * 16 + lg * 4;  // 4 consecutive k
        *(ushort4*)(Ps + qrow * 128 + (((k0 >> 3) ^ (qrow & 7)) * 16) + (k0 & 7) * 2) = pk;
      }
      lsum[qi] += rs;
    }

    // --- PV: O^T[d][q] += Vt x P (per-wave ds write->read, lgkmcnt-ordered)
    bf16x8 pf[2][2];
#pragma unroll
    for (int ks = 0; ks < 2; ++ks)
#pragma unroll
      for (int qi = 0; qi < 2; ++qi) {
        const int qrow = qi * 16 + lr;
        pf[ks][qi] = *(const bf16x8*)(Ps + qrow * 128 + (((ks * 4 + lg) ^ (qrow & 7)) * 16));
      }
    __builtin_amdgcn_s_setprio(1);
#pragma unroll
    for (int df = 0; df < 8; ++df) {
#pragma unroll
      for (int ks = 0; ks < 2; ++ks) {
        const int drow = df * 16 + lr;
        bf16x8 vfr = *(const bf16x8*)(Vs + drow * 128 + (((ks * 4 + lg) ^ (drow & 7)) * 16));
#pragma unroll
        for (int qi = 0; qi < 2; ++qi)
          acc[df][qi] = __builtin_amdgcn_mfma_f32_16x16x32_bf16(vfr, pf[ks][qi], acc[df][qi], 0, 0, 0);
      }
    }
    __builtin_amdgcn_s_setprio(0);

    __syncthreads();
    cur ^= 1;
  }

  // --- finalize: cross-lane l reduce, divide, store bf16
  const int b = bh >> 4, h = bh & 15;
#pragma unroll
  for (int qi = 0; qi < 2; ++qi) {
    float l = lsum[qi];
    l += __shfl_xor(l, 16, 64);
    l += __shfl_xor(l, 32, 64);
    const float rl = 1.0f / l;
    const int s = qw + qi * 16 + lr;
    unsigned short* orow = At + ((size_t)(b * SS + s)) * EE + h * HD;
#pragma unroll
    for (int df = 0; df < 8; ++df)
#pragma unroll
      for (int r = 0; r < 4; ++r)
        orow[df * 16 + lg * 4 + r] = f2bf(acc[df][qi][r] * rl);
  }
}

// ---------------- launcher ----------------
extern "C" void kernel_launch(void* const* d_in, const int* in_sizes, int n_in,
                              void* d_out, int out_size, void* d_ws, size_t ws_size,
                              hipStream_t stream) {
  const float* QKV = (const float*)d_in[0];
  const float* Wq  = (const float*)d_in[1];
  const float* bq  = (const float*)d_in[2];
  const float* Wk  = (const float*)d_in[3];
  const float* bk  = (const float*)d_in[4];
  const float* Wv  = (const float*)d_in[5];
  const float* bv  = (const float*)d_in[6];
  const float* Wo  = (const float*)d_in[7];
  const float* bo  = (const float*)d_in[8];
  // d_in[9] = is_causal: masking is a no-op in the reference

  unsigned short* Xb = (unsigned short*)d_out;  // dead before gemm_out writes

  char* ws = (char*)d_ws;  // 152 MiB
  unsigned short* Wqkvb = (unsigned short*)(ws);                 // [  0, 24M)
  unsigned short* Qb    = (unsigned short*)(ws + ( 24u << 20));  // [ 24, 56M)
  unsigned short* Kb    = (unsigned short*)(ws + ( 56u << 20));  // [ 56, 88M)
  unsigned short* Vb    = (unsigned short*)(ws + ( 88u << 20));  // [ 88,120M) (transposed [b,h,d,s])
  unsigned short* At    = (unsigned short*)(ws + (120u << 20));  // [120,152M)
  unsigned short* Wob   = Wqkvb;  // reuses dead Wqkv region

  cvt_f32_bf16<<<dim3(16384), dim3(256), 0, stream>>>(QKV, Xb, 4194304);
  cvt_w3<<<dim3(4096, 3), dim3(256), 0, stream>>>(Wq, Wk, Wv, Wqkvb, 1048576);

  gemm_qkv<<<dim3(24, 32), dim3(512), 0, stream>>>(Xb, Wqkvb, bq, bk, bv, Qb, Kb, Vb);
  attn_mfma<<<dim3(16, 64), dim3(256), 0, stream>>>(Qb, Kb, Vb, At);

  cvt_f32_bf16<<<dim3(4096), dim3(256), 0, stream>>>(Wo, Wob, 1048576);
  gemm_out<<<dim3(8, 32), dim3(512), 0, stream>>>(At, Wob, bo, (float*)d_out);
}

// Round 6
// 611.719 us; speedup vs baseline: 31.4008x; 1.0042x over previous
//
#include <hip/hip_runtime.h>
#include <stdint.h>

// Problem constants: B=4, S=2048, E=2048, H=16, HD=128
// Dtypes: inputs f32; OUTPUT f32. Intermediates bf16 (2% threshold).
#define BB 4
#define SS 2048
#define EE 2048
#define HH 16
#define HD 128
// SCALE * log2(e): folded into Q at the projection epilogue so attention
// softmax is pure exp2 (saves a v_mul per score element).
#define QSCALE 0.1275174490044696f

typedef __attribute__((ext_vector_type(8))) short bf16x8;
typedef __attribute__((ext_vector_type(4))) float f32x4;

__device__ __forceinline__ unsigned short f2bf(float f) {
  union { float f; unsigned u; } v;
  v.f = f;
  unsigned r = (v.u + 0x7fffu + ((v.u >> 16) & 1u)) >> 16;
  return (unsigned short)r;
}

// async global->LDS, 16B per lane. LDS dest = wave-uniform base + lane*16.
__device__ __forceinline__ void lds16(const void* g, void* l) {
  __builtin_amdgcn_global_load_lds(
      (__attribute__((address_space(1))) void*)(uintptr_t)g,
      (__attribute__((address_space(3))) void*)(uintptr_t)l,
      16, 0, 0);
}

// ---------------- fp32 -> bf16 conversion ----------------
__global__ void cvt_f32_bf16(const float* __restrict__ src,
                             unsigned short* __restrict__ dst, int n4) {
  int i = blockIdx.x * blockDim.x + threadIdx.x;
  if (i >= n4) return;
  float4 v = ((const float4*)src)[i];
  ushort4 o;
  o.x = f2bf(v.x); o.y = f2bf(v.y); o.z = f2bf(v.z); o.w = f2bf(v.w);
  ((ushort4*)dst)[i] = o;
}

// 3 weight matrices in one launch (blockIdx.y selects).
__global__ void cvt_w3(const float* __restrict__ Wq,
                       const float* __restrict__ Wk,
                       const float* __restrict__ Wv,
                       unsigned short* __restrict__ dst, int n4each) {
  const int which = blockIdx.y;
  const float* src = (which == 0) ? Wq : (which == 1) ? Wk : Wv;
  unsigned short* d = dst + (size_t)which * 4194304;
  int i = blockIdx.x * blockDim.x + threadIdx.x;
  if (i >= n4each) return;
  float4 v = ((const float4*)src)[i];
  ushort4 o;
  o.x = f2bf(v.x); o.y = f2bf(v.y); o.z = f2bf(v.z); o.w = f2bf(v.w);
  ((ushort4*)d)[i] = o;
}

// ---------------- 256x256 8-phase bt-GEMM core (m201 template) -----------
// (unchanged from r5 -- passed, qkv 261 -> <230 us)
__device__ __forceinline__ void gemm256_core(
    const unsigned short* __restrict__ A,
    const unsigned short* __restrict__ Bm,
    char* lds, int m0, int n0, f32x4 acc[8][4]) {
  const int t = threadIdx.x;
  const int w = t >> 6;
  const int ln = t & 63;
  const int lr = ln & 15;
  const int lg = ln >> 4;
  const int wr = w >> 2;   // 0..1: M half
  const int wc = w & 3;    // 0..3: N quarter

  unsigned offs[4][2];
  int dof[4][2];  // wave-uniform LDS byte offset within buffer
#pragma unroll
  for (int h = 0; h < 2; ++h)
#pragma unroll
    for (int s = 0; s < 2; ++s) {
      const int C = s * 512 + w * 64 + ln;
      const int row = C >> 3;
      const int kch = (C & 7) ^ (row & 7);
      offs[h][s]     = (unsigned)(m0 + h * 128 + row) * EE + kch * 8;
      offs[2 + h][s] = (unsigned)(n0 + h * 128 + row) * EE + kch * 8;
      dof[h][s] = h * 16384 + (s * 512 + w * 64) * 16;
      dof[2 + h][s] = 32768 + h * 16384 + (s * 512 + w * 64) * 16;
    }

#pragma unroll
  for (int i = 0; i < 8; ++i)
#pragma unroll
    for (int j = 0; j < 4; ++j) acc[i][j] = (f32x4){0.f, 0.f, 0.f, 0.f};

#pragma unroll
  for (int q = 0; q < 4; ++q)
#pragma unroll
    for (int s = 0; s < 2; ++s)
      lds16(((q < 2) ? A : Bm) + offs[q][s], lds + dof[q][s]);
  __syncthreads();

  const int cc0 = lg ^ (lr & 7);        // ks=0
  const int cc1 = (4 + lg) ^ (lr & 7);  // ks=1
  const int brbase = (wc & 1) * 64;

  bf16x8 afr[4][2];
  bf16x8 bfr[2][2][2];
  int bufo = 0;
  for (int kt = 0; kt < EE; kt += 64) {
    char* cb = lds + bufo;
    char* pb = lds + (bufo ^ 65536);
    const char* Ard = cb + wr * 16384;
    const char* Brd = cb + 32768 + (wc >> 1) * 16384;
    const bool pre = (kt + 64 < EE);
#pragma unroll
    for (int ph = 0; ph < 4; ++ph) {
      const int qm = ph >> 1, qn = ph & 1;
      if (qn == 0) {
#pragma unroll
        for (int i = 0; i < 4; ++i) {
          const int r = qm * 64 + i * 16 + lr;
          afr[i][0] = *(const bf16x8*)(Ard + r * 128 + cc0 * 16);
          afr[i][1] = *(const bf16x8*)(Ard + r * 128 + cc1 * 16);
        }
      }
      if (ph < 2) {
#pragma unroll
        for (int j = 0; j < 2; ++j) {
          const int r = brbase + ph * 32 + j * 16 + lr;
          bfr[ph][j][0] = *(const bf16x8*)(Brd + r * 128 + cc0 * 16);
          bfr[ph][j][1] = *(const bf16x8*)(Brd + r * 128 + cc1 * 16);
        }
      }
      if (pre) {
        lds16(((ph < 2) ? A : Bm) + (offs[ph][0] + (kt + 64)), pb + dof[ph][0]);
        lds16(((ph < 2) ? A : Bm) + (offs[ph][1] + (kt + 64)), pb + dof[ph][1]);
      }
      __builtin_amdgcn_s_barrier();
      __builtin_amdgcn_s_setprio(1);
#pragma unroll
      for (int i = 0; i < 4; ++i)
#pragma unroll
        for (int j = 0; j < 2; ++j) {
          acc[qm * 4 + i][qn * 2 + j] = __builtin_amdgcn_mfma_f32_16x16x32_bf16(
              afr[i][0], bfr[qn][j][0], acc[qm * 4 + i][qn * 2 + j], 0, 0, 0);
          acc[qm * 4 + i][qn * 2 + j] = __builtin_amdgcn_mfma_f32_16x16x32_bf16(
              afr[i][1], bfr[qn][j][1], acc[qm * 4 + i][qn * 2 + j], 0, 0, 0);
        }
      __builtin_amdgcn_s_setprio(0);
      if (ph < 3) {
        __builtin_amdgcn_s_barrier();  // intra-tile: buffers stable
      } else {
        __syncthreads();  // tile boundary: fence + vmcnt(0) drain + barrier
      }
    }
    bufo ^= 65536;
  }
}

// ---------------- fused QKV projection (256^2 tiles) ----------------
__global__ __launch_bounds__(512, 1)
void gemm_qkv(const unsigned short* __restrict__ X,
              const unsigned short* __restrict__ W,
              const float* __restrict__ bq,
              const float* __restrict__ bk,
              const float* __restrict__ bv,
              unsigned short* __restrict__ Qb,
              unsigned short* __restrict__ Kb,
              unsigned short* __restrict__ Vb) {
  __shared__ __align__(16) char lds[131072];
  const int m0 = blockIdx.y * 256;
  const int n0 = blockIdx.x * 256;
  f32x4 acc[8][4];
  gemm256_core(X, W, lds, m0, n0, acc);

  const int t = threadIdx.x;
  const int w = t >> 6;
  const int lr = t & 15;
  const int lg = (t & 63) >> 4;
  const int wrm = (w >> 2) * 128;
  const int wcn = (w & 3) * 64;

  const int region = n0 >> 11;  // 0=Q 1=K 2=V
  unsigned short* Dst = (region == 0) ? Qb : (region == 1) ? Kb : Vb;
  const float* bp = (region == 0) ? bq : (region == 1) ? bk : bv;

  if (region == 2) {
#pragma unroll
    for (int mi = 0; mi < 8; ++mi) {
      const int row0 = m0 + wrm + mi * 16 + lg * 4;
      const int b = row0 >> 11;
      const int s = row0 & 2047;
#pragma unroll
      for (int nj = 0; nj < 4; ++nj) {
        const int c = (n0 + wcn + nj * 16 + lr) & 2047;
        const float bias = bp[c];
        const int h = c >> 7, hd = c & 127;
        const size_t base = ((size_t)(b * HH + h) * HD + hd) * SS + s;
#pragma unroll
        for (int re = 0; re < 4; ++re)
          Dst[base + re] = f2bf(acc[mi][nj][re] + bias);
      }
    }
  } else {
    const float osc = (region == 0) ? QSCALE : 1.0f;
#pragma unroll
    for (int mi = 0; mi < 8; ++mi) {
      const int row0 = m0 + wrm + mi * 16 + lg * 4;
      const int b = row0 >> 11;
      const int s = row0 & 2047;
#pragma unroll
      for (int nj = 0; nj < 4; ++nj) {
        const int c = (n0 + wcn + nj * 16 + lr) & 2047;
        const float bias = bp[c];
        const int h = c >> 7, hd = c & 127;
        const size_t base = ((size_t)(b * HH + h) * SS + s) * HD + hd;
#pragma unroll
        for (int re = 0; re < 4; ++re)
          Dst[base + (size_t)re * HD] = f2bf((acc[mi][nj][re] + bias) * osc);
      }
    }
  }
}

// ---------------- output projection (256^2 tiles, f32 output!) -----------
__global__ __launch_bounds__(512, 1)
void gemm_out(const unsigned short* __restrict__ A,
              const unsigned short* __restrict__ W,
              const float* __restrict__ bo,
              float* __restrict__ Out) {
  __shared__ __align__(16) char lds[131072];
  const int m0 = blockIdx.y * 256;
  const int n0 = blockIdx.x * 256;
  f32x4 acc[8][4];
  gemm256_core(A, W, lds, m0, n0, acc);

  const int t = threadIdx.x;
  const int w = t >> 6;
  const int lr = t & 15;
  const int lg = (t & 63) >> 4;
  const int wrm = (w >> 2) * 128;
  const int wcn = (w & 3) * 64;

#pragma unroll
  for (int mi = 0; mi < 8; ++mi) {
    const int row0 = m0 + wrm + mi * 16 + lg * 4;
#pragma unroll
    for (int nj = 0; nj < 4; ++nj) {
      const int col = n0 + wcn + nj * 16 + lr;
      const float bias = bo[col];
#pragma unroll
      for (int re = 0; re < 4; ++re)
        Out[(size_t)(row0 + re) * EE + col] = acc[mi][nj][re] + bias;
    }
  }
}

// ---------------- MFMA flash attention (v3) ----------------
// v3 vs v2:
//  - staging addresses hoisted: 8 global src pointers precomputed, advanced
//    by fixed strides per tile (K += 64*HD elems, V += 64) -- kills ~60-80
//    VALU/tile of per-tile address recompute.
//  - P handoff fully in-register: v_cvt_pk_bf16_f32 packs P pairs, then a
//    2-round shfl_xor(32)/shfl_xor(16) butterfly redistributes so each lane
//    holds its PV B-fragment (k = 32*ks + 8*lg + m, q = lr) directly.
//    Verified lane algebra: lane lg=(a<<1|b) keeps cells kf=a+2j (round 1,
//    xor32 partner supplies the other a-half), keeps a_src==b (round 2,
//    xor16), final F[sb] = (sb==b)?Kept:Received. No P LDS, no f2bf chains.
//  - LDS 80K -> 64K: 2 blocks/CU guaranteed (2 waves/SIMD overlap).
__global__ __launch_bounds__(256, 2)
void attn_mfma(const unsigned short* __restrict__ Qb,
               const unsigned short* __restrict__ Kb,
               const unsigned short* __restrict__ Vtb,
               unsigned short* __restrict__ At) {
  // [0,32K) buf0 {K 16K, Vt 16K}; [32K,64K) buf1
  __shared__ __align__(16) char lds[65536];
  const int t = threadIdx.x;
  const int w = t >> 6;
  const int ln = t & 63;
  const int lr = ln & 15;
  const int lg = ln >> 4;
  const int la = lg >> 1;      // lane-group high bit
  const int lb = lg & 1;       // lane-group low bit
  const bool sela = (la == 0);
  const bool abeq = (la == lb);
  const bool b0eq = (lb == 0);

  const int bh = blockIdx.y;
  const int qw = blockIdx.x * 128 + w * 32;  // wave's q base within head

  const unsigned short* Qh = Qb + (size_t)bh * SS * HD;
  const unsigned short* Kh = Kb + (size_t)bh * SS * HD;
  const unsigned short* Vh = Vtb + (size_t)bh * HD * SS;  // [d][s]

  // Q fragments (B-operand): q = qw + qi*16 + lr, d = ds*32 + lg*8 + 0..7
  bf16x8 qfr[2][4];
#pragma unroll
  for (int qi = 0; qi < 2; ++qi)
#pragma unroll
    for (int ds = 0; ds < 4; ++ds)
      qfr[qi][ds] = *(const bf16x8*)(Qh + (size_t)(qw + qi * 16 + lr) * HD + ds * 32 + lg * 8);

  // O^T accumulator: acc[df][qi] holds O[q = qi*16+lr][d = df*16 + 4*lg + re]
  f32x4 acc[8][2];
#pragma unroll
  for (int df = 0; df < 8; ++df)
#pragma unroll
    for (int qi = 0; qi < 2; ++qi)
      acc[df][qi] = (f32x4){0.f, 0.f, 0.f, 0.f};
  float mrun[2] = {-3.0e38f, -3.0e38f};
  float lsum[2] = {0.f, 0.f};

  // Hoisted staging pointers (XOR pre-swizzled global sources; LDS linear).
  // K chunk c: row=c>>4, gch=(c&15)^(row&7). V chunk c: d=c>>3, kc=(c&7)^(d&7).
  const unsigned short* gk[4];
  const unsigned short* gv[4];
  int ldk[4], ldv[4];
#pragma unroll
  for (int i = 0; i < 4; ++i) {
    const int c = i * 256 + w * 64 + ln;
    const int row = c >> 4;
    const int gch = (c & 15) ^ (row & 7);
    gk[i] = Kh + (size_t)row * HD + gch * 8;
    const int d = c >> 3;
    const int kc = (c & 7) ^ (d & 7);
    gv[i] = Vh + (size_t)d * SS + kc * 8;
    ldk[i] = (i * 256 + w * 64) * 16;
    ldv[i] = 16384 + (i * 256 + w * 64) * 16;
  }

#define STAGE_KV(bufbase)                                                      \
  do {                                                                         \
    _Pragma("unroll") for (int i = 0; i < 4; ++i) {                            \
      lds16(gk[i], (bufbase) + ldk[i]);                                        \
      lds16(gv[i], (bufbase) + ldv[i]);                                        \
    }                                                                          \
    _Pragma("unroll") for (int i = 0; i < 4; ++i) {                            \
      gk[i] += 64 * HD;                                                        \
      gv[i] += 64;                                                             \
    }                                                                          \
  } while (0)

  STAGE_KV(lds);
  __syncthreads();  // implicit vmcnt(0): tile 0 landed

  int cur = 0;
  for (int kt = 0; kt < SS; kt += 64) {
    if (kt + 64 < SS) STAGE_KV(lds + ((cur ^ 1) * 32768));

    char* Ks = lds + cur * 32768;
    char* Vs = Ks + 16384;

    // --- QK^T (swapped): St[k = kf*16 + 4*lg + re][q = qi*16 + lr]
    f32x4 st[4][2];
    __builtin_amdgcn_s_setprio(1);
#pragma unroll
    for (int kf = 0; kf < 4; ++kf) {
#pragma unroll
      for (int qi = 0; qi < 2; ++qi) st[kf][qi] = (f32x4){0.f, 0.f, 0.f, 0.f};
#pragma unroll
      for (int ds = 0; ds < 4; ++ds) {
        const int krow = kf * 16 + lr;
        bf16x8 kfr = *(const bf16x8*)(Ks + krow * 256 + (((ds * 4 + lg) ^ (krow & 7)) * 16));
#pragma unroll
        for (int qi = 0; qi < 2; ++qi)
          st[kf][qi] = __builtin_amdgcn_mfma_f32_16x16x32_bf16(kfr, qfr[qi][ds], st[kf][qi], 0, 0, 0);
      }
    }
    __builtin_amdgcn_s_setprio(0);

    // --- online softmax + in-register P->bf16 handoff
    bf16x8 pf[2][2];  // [ks][qi] PV B-operand fragments
#pragma unroll
    for (int qi = 0; qi < 2; ++qi) {
      float tm = st[0][qi][0];
#pragma unroll
      for (int kf = 0; kf < 4; ++kf)
#pragma unroll
        for (int r = 0; r < 4; ++r) tm = fmaxf(tm, st[kf][qi][r]);
      tm = fmaxf(tm, __shfl_xor(tm, 16, 64));
      tm = fmaxf(tm, __shfl_xor(tm, 32, 64));
      if (!__all(tm <= mrun[qi] + 8.0f)) {
        const float mnew = fmaxf(mrun[qi], tm);
        const float alpha = __builtin_exp2f(mrun[qi] - mnew);
        mrun[qi] = mnew;
        lsum[qi] *= alpha;
#pragma unroll
        for (int df = 0; df < 8; ++df) {
          acc[df][qi][0] *= alpha; acc[df][qi][1] *= alpha;
          acc[df][qi][2] *= alpha; acc[df][qi][3] *= alpha;
        }
      }
      const float mcur = mrun[qi];
      float rs = 0.f;
      // cells: cell[kf][i] = pack(p[2i], p[2i+1]); k = kf*16 + 4*lg + 2i+b0
      unsigned cell[4][2];
#pragma unroll
      for (int kf = 0; kf < 4; ++kf) {
        const float p0 = __builtin_exp2f(st[kf][qi][0] - mcur);
        const float p1 = __builtin_exp2f(st[kf][qi][1] - mcur);
        const float p2 = __builtin_exp2f(st[kf][qi][2] - mcur);
        const float p3 = __builtin_exp2f(st[kf][qi][3] - mcur);
        rs += (p0 + p1) + (p2 + p3);
        asm("v_cvt_pk_bf16_f32 %0, %1, %2" : "=v"(cell[kf][0]) : "v"(p0), "v"(p1));
        asm("v_cvt_pk_bf16_f32 %0, %1, %2" : "=v"(cell[kf][1]) : "v"(p2), "v"(p3));
      }
      lsum[qi] += rs;

      // Butterfly round 1 (xor32, flips la): keep kf&1==la halves.
      unsigned own1[2][2], rcv1[2][2];
#pragma unroll
      for (int j = 0; j < 2; ++j)
#pragma unroll
        for (int i = 0; i < 2; ++i) {
          const unsigned snd = sela ? cell[2 * j + 1][i] : cell[2 * j][i];
          rcv1[j][i] = (unsigned)__shfl_xor((int)snd, 32, 64);
          own1[j][i] = sela ? cell[2 * j][i] : cell[2 * j + 1][i];
        }
      // Round 2 (xor16, flips lb): keep a_src==lb.
      unsigned kp[2][2], rr[2][2];
#pragma unroll
      for (int j = 0; j < 2; ++j)
#pragma unroll
        for (int i = 0; i < 2; ++i) {
          const unsigned s2 = abeq ? rcv1[j][i] : own1[j][i];
          rr[j][i] = (unsigned)__shfl_xor((int)s2, 16, 64);
          kp[j][i] = abeq ? own1[j][i] : rcv1[j][i];
        }
      // Assemble B-frags: word m/2: F[sb][i], sb = m>>2, F[sb]=(sb==lb)?kp:rr
#pragma unroll
      for (int ks = 0; ks < 2; ++ks) {
        union { unsigned u[4]; bf16x8 v; } pk;
        pk.u[0] = b0eq ? kp[ks][0] : rr[ks][0];
        pk.u[1] = b0eq ? kp[ks][1] : rr[ks][1];
        pk.u[2] = b0eq ? rr[ks][0] : kp[ks][0];
        pk.u[3] = b0eq ? rr[ks][1] : kp[ks][1];
        pf[ks][qi] = pk.v;
      }
    }

    // --- PV: O^T[d][q] += Vt x P (P fragments now in registers)
    __builtin_amdgcn_s_setprio(1);
#pragma unroll
    for (int df = 0; df < 8; ++df) {
#pragma unroll
      for (int ks = 0; ks < 2; ++ks) {
        const int drow = df * 16 + lr;
        bf16x8 vfr = *(const bf16x8*)(Vs + drow * 128 + (((ks * 4 + lg) ^ (drow & 7)) * 16));
#pragma unroll
        for (int qi = 0; qi < 2; ++qi)
          acc[df][qi] = __builtin_amdgcn_mfma_f32_16x16x32_bf16(vfr, pf[ks][qi], acc[df][qi], 0, 0, 0);
      }
    }
    __builtin_amdgcn_s_setprio(0);

    __syncthreads();
    cur ^= 1;
  }

  // --- finalize: cross-lane l reduce, divide, store bf16
  const int b = bh >> 4, h = bh & 15;
#pragma unroll
  for (int qi = 0; qi < 2; ++qi) {
    float l = lsum[qi];
    l += __shfl_xor(l, 16, 64);
    l += __shfl_xor(l, 32, 64);
    const float rl = 1.0f / l;
    const int s = qw + qi * 16 + lr;
    unsigned short* orow = At + ((size_t)(b * SS + s)) * EE + h * HD;
#pragma unroll
    for (int df = 0; df < 8; ++df)
#pragma unroll
      for (int r = 0; r < 4; ++r)
        orow[df * 16 + lg * 4 + r] = f2bf(acc[df][qi][r] * rl);
  }
}

// ---------------- launcher ----------------
extern "C" void kernel_launch(void* const* d_in, const int* in_sizes, int n_in,
                              void* d_out, int out_size, void* d_ws, size_t ws_size,
                              hipStream_t stream) {
  const float* QKV = (const float*)d_in[0];
  const float* Wq  = (const float*)d_in[1];
  const float* bq  = (const float*)d_in[2];
  const float* Wk  = (const float*)d_in[3];
  const float* bk  = (const float*)d_in[4];
  const float* Wv  = (const float*)d_in[5];
  const float* bv  = (const float*)d_in[6];
  const float* Wo  = (const float*)d_in[7];
  const float* bo  = (const float*)d_in[8];
  // d_in[9] = is_causal: masking is a no-op in the reference

  unsigned short* Xb = (unsigned short*)d_out;  // dead before gemm_out writes

  char* ws = (char*)d_ws;  // 152 MiB
  unsigned short* Wqkvb = (unsigned short*)(ws);                 // [  0, 24M)
  unsigned short* Qb    = (unsigned short*)(ws + ( 24u << 20));  // [ 24, 56M)
  unsigned short* Kb    = (unsigned short*)(ws + ( 56u << 20));  // [ 56, 88M)
  unsigned short* Vb    = (unsigned short*)(ws + ( 88u << 20));  // [ 88,120M) (transposed [b,h,d,s])
  unsigned short* At    = (unsigned short*)(ws + (120u << 20));  // [120,152M)
  unsigned short* Wob   = Wqkvb;  // reuses dead Wqkv region

  cvt_f32_bf16<<<dim3(16384), dim3(256), 0, stream>>>(QKV, Xb, 4194304);
  cvt_w3<<<dim3(4096, 3), dim3(256), 0, stream>>>(Wq, Wk, Wv, Wqkvb, 1048576);

  gemm_qkv<<<dim3(24, 32), dim3(512), 0, stream>>>(Xb, Wqkvb, bq, bk, bv, Qb, Kb, Vb);
  attn_mfma<<<dim3(16, 64), dim3(256), 0, stream>>>(Qb, Kb, Vb, At);

  cvt_f32_bf16<<<dim3(4096), dim3(256), 0, stream>>>(Wo, Wob, 1048576);
  gemm_out<<<dim3(8, 32), dim3(512), 0, stream>>>(At, Wob, bo, (float*)d_out);
}